// Round 5
// baseline (154.542 us; speedup 1.0000x reference)
//
#include <hip/hip_runtime.h>
#include <hip/hip_bf16.h>
#include <stdint.h>

// out = quantize(relu(x @ w + b)), x:8192x1024 f32 (fixed-point 2^-16 grid),
// w:1024x1024 f32 (grid), b:1024 zeros.
// 3-limb-product bf16 decomposition: x = xh+xm, w = wh+wl.
//   y ~= xh*wh + xm*wh + xh*wl   (dropped terms ~3e-5 rms << 0.0156 tolerance)
// Virtual K' = 3*1024 = 3072 over A2 = [xh|xm] (8192x2048), Bt2 = [wh|wl]^T.
// GEMM: 256x128 tile, BK=64, 8 waves (4Mx2N, 64x64/wave), 3-deep circular
// LDS pipeline (144 KB), 4 phases per K-tile (8-phase-template style:
// ds_read + stage-issue -> s_barrier -> lgkmcnt(0) -> setprio MFMA -> barrier),
// ONE counted s_waitcnt vmcnt(6) per K-tile (T4 - never drain to 0 in loop),
// XOR bank swizzle (rule 21 both-sides), bijective XCD swizzle (T1).

typedef __attribute__((ext_vector_type(8))) short short8;
typedef __attribute__((ext_vector_type(4))) float f32x4;
typedef __attribute__((ext_vector_type(4))) unsigned short us4;
typedef __attribute__((ext_vector_type(8))) unsigned short us8;

__device__ __forceinline__ unsigned short f32_to_bf16_rne(float f) {
    uint32_t u = __float_as_uint(f);
    uint32_t r = u + 0x7FFFu + ((u >> 16) & 1u);
    return (unsigned short)(r >> 16);
}
__device__ __forceinline__ float bf16_to_f32(unsigned short s) {
    return __uint_as_float(((uint32_t)s) << 16);
}

// ---------------- split x into 2 exact bf16 limbs (8 elem/thread, 16B stores) ----
__global__ __launch_bounds__(256) void split_x_kernel(const float* __restrict__ x,
                                                      unsigned short* __restrict__ A2) {
    int i = blockIdx.x * 256 + threadIdx.x;       // 8-elem index, 1048576 total
    int e = i * 8;
    int row = e >> 10;
    int col = e & 1023;
    float4 v0 = reinterpret_cast<const float4*>(x)[2 * i];
    float4 v1 = reinterpret_cast<const float4*>(x)[2 * i + 1];
    float vv[8] = {v0.x, v0.y, v0.z, v0.w, v1.x, v1.y, v1.z, v1.w};
    us8 h, m;
    unsigned short* hp = (unsigned short*)&h;
    unsigned short* mp = (unsigned short*)&m;
#pragma unroll
    for (int j = 0; j < 8; ++j) {
        float f = vv[j];
        unsigned short hb = f32_to_bf16_rne(f);
        float r1 = f - bf16_to_f32(hb);
        unsigned short mb = f32_to_bf16_rne(r1);
        hp[j] = hb; mp[j] = mb;
    }
    size_t base = (size_t)row * 2048 + col;
    *reinterpret_cast<us8*>(&A2[base])        = h;
    *reinterpret_cast<us8*>(&A2[base + 1024]) = m;
}

// ---------------- transpose + split w into 2 exact bf16 limbs ----------------
__global__ __launch_bounds__(1024) void split_w_kernel(const float* __restrict__ w,
                                                       unsigned short* __restrict__ Bt2) {
    __shared__ float ts[32][33];
    int tx = threadIdx.x, ty = threadIdx.y;
    int n0 = blockIdx.x * 32, k0 = blockIdx.y * 32;
    ts[ty][tx] = w[(size_t)(k0 + ty) * 1024 + (n0 + tx)];
    __syncthreads();
    float f = ts[tx][ty];                      // = w[k0+tx][n0+ty]
    unsigned short h = f32_to_bf16_rne(f);
    float r = f - bf16_to_f32(h);
    unsigned short l = f32_to_bf16_rne(r);
    int n = n0 + ty, k = k0 + tx;
    Bt2[(size_t)n * 2048 + k]        = h;
    Bt2[(size_t)n * 2048 + 1024 + k] = l;
}

// ---------------- GEMM ----------------
#define BM 256
#define BN 128
#define BK 64
#define NT 48   // 3 limb-product blocks x 16 sub-tiles of 64

__device__ __forceinline__ void load16_to_lds(const void* g, void* l) {
    __builtin_amdgcn_global_load_lds(
        (const __attribute__((address_space(1))) unsigned int*)g,
        (__attribute__((address_space(3))) unsigned int*)l,
        16, 0, 0);
}

__global__ __launch_bounds__(512, 2) void gemm_kernel(const unsigned short* __restrict__ A2,
                                                      const unsigned short* __restrict__ Bt2,
                                                      const float* __restrict__ bias,
                                                      float* __restrict__ out) {
    __shared__ unsigned short As[3][BM * BK];   // 3 x 32 KB
    __shared__ unsigned short Bs[3][BN * BK];   // 3 x 16 KB  -> 144 KB total

    const int tid  = threadIdx.x;
    const int lane = tid & 63;
    const int wave = tid >> 6;
    const int wr = wave >> 1, wc = wave & 1;    // 4M x 2N waves, each 64x64 out

    // Bijective XCD swizzle: grid=256, xcd=bid%8 owns bm {4*xcd..4*xcd+3} x all bn
    const int bid = blockIdx.x;
    const int wg  = (bid & 7) * 32 + (bid >> 3);
    const int bm = wg >> 3, bn = wg & 7;
    const int m0 = bm * BM, n0 = bn * BN;

    f32x4 acc[4][4];
#pragma unroll
    for (int i = 0; i < 4; ++i)
#pragma unroll
        for (int j = 0; j < 4; ++j) acc[i][j] = (f32x4)0.0f;

    // A limb segments over virtual-K blocks [h, m, h]; B segments [wh, wh, wl]
    auto aoff_of = [&](int t) { int blk = t >> 4; return ((blk == 1) ? 1024 : 0) + (t & 15) * 64; };
    auto boff_of = [&](int t) { int blk = t >> 4; return ((blk == 2) ? 1024 : 0) + (t & 15) * 64; };

    auto stageA = [&](int b, int aoff, int it) {
        int c = it * 512 + tid;                 // 16B chunk id, 0..2047
        int row = c >> 3;
        int sw = (c & 7) ^ (row & 7);           // pre-swizzled global source
        load16_to_lds(A2 + (size_t)(m0 + row) * 2048 + aoff + sw * 8,
                      (char*)As[b] + c * 16);
    };
    auto stageBf = [&](int b, int boff, int it) {
        int c = it * 512 + tid;                 // 0..1023
        int row = c >> 3;
        int sw = (c & 7) ^ (row & 7);
        load16_to_lds(Bt2 + (size_t)(n0 + row) * 2048 + boff + sw * 8,
                      (char*)Bs[b] + c * 16);
    };

    // one K-tile = 4 phases; stage loads for tile t+2 interleaved (2A,2A,2B,-)
    auto do_tile = [&](int b, int t, bool doStage, int nb) {
        const char* Ab = (const char*)As[b];
        const char* Bb = (const char*)Bs[b];
        const int aoff2 = aoff_of(t + 2);
        const int boff2 = boff_of(t + 2);
        short8 af[4], bf[2];
        // ---- P0: kk=0, n-half 0 ----
        {
            const int ch = (lane >> 4);
#pragma unroll
            for (int f = 0; f < 4; ++f) {
                int ar = wr * 64 + f * 16 + (lane & 15);
                af[f] = *reinterpret_cast<const short8*>(Ab + ar * 128 + ((ch ^ (ar & 7)) << 4));
            }
#pragma unroll
            for (int j = 0; j < 2; ++j) {
                int br = wc * 64 + j * 16 + (lane & 15);
                bf[j] = *reinterpret_cast<const short8*>(Bb + br * 128 + ((ch ^ (br & 7)) << 4));
            }
            if (doStage) { stageA(nb, aoff2, 0); stageA(nb, aoff2, 1); }
            __builtin_amdgcn_s_barrier();
            asm volatile("s_waitcnt lgkmcnt(0)" ::: "memory");
            __builtin_amdgcn_sched_barrier(0);
            __builtin_amdgcn_s_setprio(1);
#pragma unroll
            for (int i = 0; i < 4; ++i)
#pragma unroll
                for (int j = 0; j < 2; ++j)
                    acc[i][j] = __builtin_amdgcn_mfma_f32_16x16x32_bf16(af[i], bf[j], acc[i][j], 0, 0, 0);
            __builtin_amdgcn_s_setprio(0);
            __builtin_amdgcn_s_barrier();
        }
        // ---- P1: kk=0, n-half 1 ----
        {
            const int ch = (lane >> 4);
#pragma unroll
            for (int j = 0; j < 2; ++j) {
                int br = wc * 64 + (2 + j) * 16 + (lane & 15);
                bf[j] = *reinterpret_cast<const short8*>(Bb + br * 128 + ((ch ^ (br & 7)) << 4));
            }
            if (doStage) { stageA(nb, aoff2, 2); stageA(nb, aoff2, 3); }
            __builtin_amdgcn_s_barrier();
            asm volatile("s_waitcnt lgkmcnt(0)" ::: "memory");
            __builtin_amdgcn_sched_barrier(0);
            __builtin_amdgcn_s_setprio(1);
#pragma unroll
            for (int i = 0; i < 4; ++i)
#pragma unroll
                for (int j = 0; j < 2; ++j)
                    acc[i][2 + j] = __builtin_amdgcn_mfma_f32_16x16x32_bf16(af[i], bf[j], acc[i][2 + j], 0, 0, 0);
            __builtin_amdgcn_s_setprio(0);
            __builtin_amdgcn_s_barrier();
        }
        // ---- P2: kk=1, n-half 0 ----
        {
            const int ch = 4 + (lane >> 4);
#pragma unroll
            for (int f = 0; f < 4; ++f) {
                int ar = wr * 64 + f * 16 + (lane & 15);
                af[f] = *reinterpret_cast<const short8*>(Ab + ar * 128 + ((ch ^ (ar & 7)) << 4));
            }
#pragma unroll
            for (int j = 0; j < 2; ++j) {
                int br = wc * 64 + j * 16 + (lane & 15);
                bf[j] = *reinterpret_cast<const short8*>(Bb + br * 128 + ((ch ^ (br & 7)) << 4));
            }
            if (doStage) { stageBf(nb, boff2, 0); stageBf(nb, boff2, 1); }
            __builtin_amdgcn_s_barrier();
            asm volatile("s_waitcnt lgkmcnt(0)" ::: "memory");
            __builtin_amdgcn_sched_barrier(0);
            __builtin_amdgcn_s_setprio(1);
#pragma unroll
            for (int i = 0; i < 4; ++i)
#pragma unroll
                for (int j = 0; j < 2; ++j)
                    acc[i][j] = __builtin_amdgcn_mfma_f32_16x16x32_bf16(af[i], bf[j], acc[i][j], 0, 0, 0);
            __builtin_amdgcn_s_setprio(0);
            __builtin_amdgcn_s_barrier();
        }
        // ---- P3: kk=1, n-half 1 ----
        {
            const int ch = 4 + (lane >> 4);
#pragma unroll
            for (int j = 0; j < 2; ++j) {
                int br = wc * 64 + (2 + j) * 16 + (lane & 15);
                bf[j] = *reinterpret_cast<const short8*>(Bb + br * 128 + ((ch ^ (br & 7)) << 4));
            }
            __builtin_amdgcn_s_barrier();
            asm volatile("s_waitcnt lgkmcnt(0)" ::: "memory");
            __builtin_amdgcn_sched_barrier(0);
            __builtin_amdgcn_s_setprio(1);
#pragma unroll
            for (int i = 0; i < 4; ++i)
#pragma unroll
                for (int j = 0; j < 2; ++j)
                    acc[i][2 + j] = __builtin_amdgcn_mfma_f32_16x16x32_bf16(af[i], bf[j], acc[i][2 + j], 0, 0, 0);
            __builtin_amdgcn_s_setprio(0);
            // trailing barrier merged with end-of-tile barrier in caller
        }
    };

    // prologue: fully stage tiles 0 and 1 (6 loads each)
#pragma unroll
    for (int it = 0; it < 4; ++it) stageA(0, aoff_of(0), it);
#pragma unroll
    for (int it = 0; it < 2; ++it) stageBf(0, boff_of(0), it);
#pragma unroll
    for (int it = 0; it < 4; ++it) stageA(1, aoff_of(1), it);
#pragma unroll
    for (int it = 0; it < 2; ++it) stageBf(1, boff_of(1), it);
    asm volatile("s_waitcnt vmcnt(6)" ::: "memory");   // tile 0 resident
    __builtin_amdgcn_s_barrier();

    int cur = 0;
#pragma unroll 1
    for (int t = 0; t < NT - 2; ++t) {
        int nb = (cur == 0) ? 2 : cur - 1;             // (t+2)%3
        do_tile(cur, t, true, nb);
        asm volatile("s_waitcnt vmcnt(6)" ::: "memory"); // tile t+1 resident; t+2 in flight
        __builtin_amdgcn_s_barrier();
        cur = (cur == 2) ? 0 : cur + 1;
    }
    do_tile(cur, NT - 2, false, 0);
    asm volatile("s_waitcnt vmcnt(0)" ::: "memory");   // last tile resident
    __builtin_amdgcn_s_barrier();
    cur = (cur == 2) ? 0 : cur + 1;
    do_tile(cur, NT - 1, false, 0);

    // epilogue: bias + relu + quantize (RNE matches jnp.round)
    const int colBase = n0 + wc * 64 + (lane & 15);
    const int rowBase = m0 + wr * 64 + ((lane >> 4) << 2);
#pragma unroll
    for (int i = 0; i < 4; ++i) {
#pragma unroll
        for (int j = 0; j < 4; ++j) {
            int col = colBase + j * 16;
            float bv = bias[col];
#pragma unroll
            for (int r = 0; r < 4; ++r) {
                int row = rowBase + i * 16 + r;
                float y = acc[i][j][r] + bv;
                y = fmaxf(y, 0.0f);
                y = rintf(y * 65536.0f) * (1.0f / 65536.0f);
                out[(size_t)row * 1024 + col] = y;
            }
        }
    }
}

// ---------------- fallback (ws too small): naive fp32 ----------------
__global__ __launch_bounds__(256) void naive_kernel(const float* __restrict__ x,
                                                    const float* __restrict__ w,
                                                    const float* __restrict__ bias,
                                                    float* __restrict__ out) {
    int idx = blockIdx.x * 256 + threadIdx.x;
    int row = idx >> 10, col = idx & 1023;
    float s = bias[col];
    for (int k = 0; k < 1024; ++k)
        s += x[(size_t)row * 1024 + k] * w[(size_t)k * 1024 + col];
    s = fmaxf(s, 0.0f);
    out[idx] = rintf(s * 65536.0f) * (1.0f / 65536.0f);
}

extern "C" void kernel_launch(void* const* d_in, const int* in_sizes, int n_in,
                              void* d_out, int out_size, void* d_ws, size_t ws_size,
                              hipStream_t stream) {
    const float* x = (const float*)d_in[0];
    const float* w = (const float*)d_in[1];
    const float* b = (const float*)d_in[2];
    float* out = (float*)d_out;

    const size_t needA = (size_t)8192 * 2048 * 2;   // 32 MB
    const size_t needB = (size_t)1024 * 2048 * 2;   //  4 MB
    if (ws_size < needA + needB) {
        naive_kernel<<<(8192 * 1024) / 256, 256, 0, stream>>>(x, w, b, out);
        return;
    }
    unsigned short* A2  = (unsigned short*)d_ws;
    unsigned short* Bt2 = (unsigned short*)((char*)d_ws + needA);

    split_x_kernel<<<(8192 * 1024 / 8) / 256, 256, 0, stream>>>(x, A2);
    split_w_kernel<<<dim3(32, 32), dim3(32, 32), 0, stream>>>(w, Bt2);
    gemm_kernel<<<256, 512, 0, stream>>>(A2, Bt2, b, out);
}

// Round 7
// 150.109 us; speedup vs baseline: 1.0295x; 1.0295x over previous
//
#include <hip/hip_runtime.h>
#include <hip/hip_bf16.h>
#include <stdint.h>

// out = quantize(relu(x @ w + b)), x:8192x1024 f32 (fixed-point 2^-16 grid),
// w:1024x1024 f32 (grid), b:1024 zeros.
// 3-limb-product bf16 decomposition: x = xh+xm, w = wh+wl.
//   y ~= xh*wh + xm*wh + xh*wl   (dropped terms ~3e-5 rms << 0.0156 tolerance)
// Virtual K' = 3*1024 = 3072 over A2 = [xh|xm] (8192x2048), Bt2 = [wh|wl]^T.
// GEMM r6: 256x128 tile, BK=64, 8 waves (4Mx2N, 64x64/wave), 3-deep circular
// LDS (144 KB), 2 phases/K-tile x 16 MFMA, ALL addresses hoisted to registers
// (r5 post-mortem: VALUBusy 16% = per-phase addr recompute), compile-time
// buffer indices via 3x-unrolled loop, NO per-phase lgkm/sched_barrier pins
// (m141: pinning defeats compiler scheduling), one lgkmcnt(0) per tile-end
// (cross-wave buffer-reuse safety), counted vmcnt(6)/tile, setprio on MFMA,
// XOR bank swizzle (rule 21 both-sides), bijective XCD swizzle (T1).

typedef __attribute__((ext_vector_type(8))) short short8;
typedef __attribute__((ext_vector_type(4))) float f32x4;
typedef __attribute__((ext_vector_type(8))) unsigned short us8;

template <int N> struct IC { static constexpr int v = N; };

__device__ __forceinline__ unsigned short f32_to_bf16_rne(float f) {
    uint32_t u = __float_as_uint(f);
    uint32_t r = u + 0x7FFFu + ((u >> 16) & 1u);
    return (unsigned short)(r >> 16);
}
__device__ __forceinline__ float bf16_to_f32(unsigned short s) {
    return __uint_as_float(((uint32_t)s) << 16);
}

// ---------------- split x into 2 exact bf16 limbs (8 elem/thread, 16B stores) ----
__global__ __launch_bounds__(256) void split_x_kernel(const float* __restrict__ x,
                                                      unsigned short* __restrict__ A2) {
    int i = blockIdx.x * 256 + threadIdx.x;       // 8-elem index, 1048576 total
    int e = i * 8;
    int row = e >> 10;
    int col = e & 1023;
    float4 v0 = reinterpret_cast<const float4*>(x)[2 * i];
    float4 v1 = reinterpret_cast<const float4*>(x)[2 * i + 1];
    float vv[8] = {v0.x, v0.y, v0.z, v0.w, v1.x, v1.y, v1.z, v1.w};
    us8 h, m;
    unsigned short* hp = (unsigned short*)&h;
    unsigned short* mp = (unsigned short*)&m;
#pragma unroll
    for (int j = 0; j < 8; ++j) {
        float f = vv[j];
        unsigned short hb = f32_to_bf16_rne(f);
        float r1 = f - bf16_to_f32(hb);
        unsigned short mb = f32_to_bf16_rne(r1);
        hp[j] = hb; mp[j] = mb;
    }
    size_t base = (size_t)row * 2048 + col;
    *reinterpret_cast<us8*>(&A2[base])        = h;
    *reinterpret_cast<us8*>(&A2[base + 1024]) = m;
}

// ---------------- transpose + split w into 2 exact bf16 limbs ----------------
__global__ __launch_bounds__(1024) void split_w_kernel(const float* __restrict__ w,
                                                       unsigned short* __restrict__ Bt2) {
    __shared__ float ts[32][33];
    int tx = threadIdx.x, ty = threadIdx.y;
    int n0 = blockIdx.x * 32, k0 = blockIdx.y * 32;
    ts[ty][tx] = w[(size_t)(k0 + ty) * 1024 + (n0 + tx)];
    __syncthreads();
    float f = ts[tx][ty];                      // = w[k0+tx][n0+ty]
    unsigned short h = f32_to_bf16_rne(f);
    float r = f - bf16_to_f32(h);
    unsigned short l = f32_to_bf16_rne(r);
    int n = n0 + ty, k = k0 + tx;
    Bt2[(size_t)n * 2048 + k]        = h;
    Bt2[(size_t)n * 2048 + 1024 + k] = l;
}

// ---------------- GEMM ----------------
#define BM 256
#define BN 128
#define BK 64
#define NT 48   // 3 limb-product blocks x 16 sub-tiles of 64

__device__ __forceinline__ void load16_to_lds(const void* g, void* l) {
    __builtin_amdgcn_global_load_lds(
        (const __attribute__((address_space(1))) unsigned int*)g,
        (__attribute__((address_space(3))) unsigned int*)l,
        16, 0, 0);
}

__device__ __forceinline__ void rd4(short8* dst, const void* base, const int* offs) {
#pragma unroll
    for (int f = 0; f < 4; ++f)
        dst[f] = *reinterpret_cast<const short8*>((const char*)base + offs[f]);
}

__device__ __forceinline__ void mfma16(f32x4 (&acc)[4][4], const short8* af, const short8* bf) {
#pragma unroll
    for (int i = 0; i < 4; ++i)
#pragma unroll
        for (int j = 0; j < 4; ++j)
            acc[i][j] = __builtin_amdgcn_mfma_f32_16x16x32_bf16(af[i], bf[j], acc[i][j], 0, 0, 0);
}

__global__ __launch_bounds__(512, 2) void gemm_kernel(const unsigned short* __restrict__ A2,
                                                      const unsigned short* __restrict__ Bt2,
                                                      const float* __restrict__ bias,
                                                      float* __restrict__ out) {
    __shared__ unsigned short As[3][BM * BK];   // 3 x 32 KB
    __shared__ unsigned short Bs[3][BN * BK];   // 3 x 16 KB  -> 144 KB total

    const int tid  = threadIdx.x;
    const int lane = tid & 63;
    const int wave = tid >> 6;
    const int wr = wave >> 1, wc = wave & 1;    // 4M x 2N waves, each 64x64 out

    // Bijective XCD swizzle: grid=256, xcd=bid%8 owns bm {4*xcd..4*xcd+3} x all bn
    const int bid = blockIdx.x;
    const int wg  = (bid & 7) * 32 + (bid >> 3);
    const int bm = wg >> 3, bn = wg & 7;
    const int m0 = bm * BM, n0 = bn * BN;

    f32x4 acc[4][4];
#pragma unroll
    for (int i = 0; i < 4; ++i)
#pragma unroll
        for (int j = 0; j < 4; ++j) acc[i][j] = (f32x4)0.0f;

    // ---- hoisted ds_read byte offsets (buffer-relative), fixed per thread ----
    int a0[4], a1[4], b0[4], b1[4];
    {
        const int ch0 = lane >> 4, ch1 = 4 + (lane >> 4);
#pragma unroll
        for (int f = 0; f < 4; ++f) {
            int ar = wr * 64 + f * 16 + (lane & 15);
            a0[f] = ar * 128 + ((ch0 ^ (ar & 7)) << 4);
            a1[f] = ar * 128 + ((ch1 ^ (ar & 7)) << 4);
            int br = wc * 64 + f * 16 + (lane & 15);
            b0[f] = br * 128 + ((ch0 ^ (br & 7)) << 4);
            b1[f] = br * 128 + ((ch1 ^ (br & 7)) << 4);
        }
    }
    // ---- hoisted stage offsets (element offsets; uniform segment ptr added/tile) ----
    int aTh[4], bTh[2];
#pragma unroll
    for (int it = 0; it < 4; ++it) {
        int c = it * 512 + tid, row = c >> 3, sw = (c & 7) ^ (row & 7);
        aTh[it] = (m0 + row) * 2048 + sw * 8;
    }
#pragma unroll
    for (int it = 0; it < 2; ++it) {
        int c = it * 512 + tid, row = c >> 3, sw = (c & 7) ^ (row & 7);
        bTh[it] = (n0 + row) * 2048 + sw * 8;
    }
    const int dst16 = tid * 16;

    // A limb segments over virtual-K blocks [h, m, h]; B segments [wh, wh, wl]
    auto aoff_of = [](int t) { int blk = t >> 4; return ((blk == 1) ? 1024 : 0) + (t & 15) * 64; };
    auto boff_of = [](int t) { int blk = t >> 4; return ((blk == 2) ? 1024 : 0) + (t & 15) * 64; };

    // one K-tile: 2 phases x {8 ds_read + 3 stage-issue, barrier, setprio 16 MFMA, barrier}
    // buffer indices B/NB are compile-time (IC<>), so LDS bases constant-fold.
    auto tile = [&](auto BC, auto NBC, int t, bool doStage) {
        constexpr int B  = decltype(BC)::v;
        constexpr int NB = decltype(NBC)::v;
        short8 af[4], bf[4];
        // ---- P0: kk=0 ----
        rd4(af, As[B], a0);
        rd4(bf, Bs[B], b0);
        if (doStage) {
            const unsigned short* pA_ = A2 + aoff_of(t + 2);
            load16_to_lds(pA_ + aTh[0], (char*)As[NB] + 0 * 8192 + dst16);
            load16_to_lds(pA_ + aTh[1], (char*)As[NB] + 1 * 8192 + dst16);
            load16_to_lds(pA_ + aTh[2], (char*)As[NB] + 2 * 8192 + dst16);
        }
        __builtin_amdgcn_s_barrier();
        __builtin_amdgcn_s_setprio(1);
        mfma16(acc, af, bf);
        __builtin_amdgcn_s_setprio(0);
        __builtin_amdgcn_s_barrier();
        // ---- P1: kk=1 ----
        rd4(af, As[B], a1);
        rd4(bf, Bs[B], b1);
        if (doStage) {
            const unsigned short* pA_ = A2 + aoff_of(t + 2);
            const unsigned short* pB_ = Bt2 + boff_of(t + 2);
            load16_to_lds(pA_ + aTh[3], (char*)As[NB] + 3 * 8192 + dst16);
            load16_to_lds(pB_ + bTh[0], (char*)Bs[NB] + 0 * 8192 + dst16);
            load16_to_lds(pB_ + bTh[1], (char*)Bs[NB] + 1 * 8192 + dst16);
        }
        __builtin_amdgcn_s_barrier();
        __builtin_amdgcn_s_setprio(1);
        mfma16(acc, af, bf);
        __builtin_amdgcn_s_setprio(0);
        // drain this tile's ds_reads before end barrier: after the barrier other
        // waves' global_load_lds may overwrite buffer (t+3)%3 == B-next cycle.
        asm volatile("s_waitcnt lgkmcnt(0)" ::: "memory");
    };

    // prologue: fully stage tiles 0 (buf0, oldest 6) then 1 (buf1)
    {
        const unsigned short* pA_ = A2 + aoff_of(0);
        const unsigned short* pB_ = Bt2 + boff_of(0);
        load16_to_lds(pA_ + aTh[0], (char*)As[0] + 0 * 8192 + dst16);
        load16_to_lds(pA_ + aTh[1], (char*)As[0] + 1 * 8192 + dst16);
        load16_to_lds(pA_ + aTh[2], (char*)As[0] + 2 * 8192 + dst16);
        load16_to_lds(pA_ + aTh[3], (char*)As[0] + 3 * 8192 + dst16);
        load16_to_lds(pB_ + bTh[0], (char*)Bs[0] + 0 * 8192 + dst16);
        load16_to_lds(pB_ + bTh[1], (char*)Bs[0] + 1 * 8192 + dst16);
        const unsigned short* qA_ = A2 + aoff_of(1);
        const unsigned short* qB_ = Bt2 + boff_of(1);
        load16_to_lds(qA_ + aTh[0], (char*)As[1] + 0 * 8192 + dst16);
        load16_to_lds(qA_ + aTh[1], (char*)As[1] + 1 * 8192 + dst16);
        load16_to_lds(qA_ + aTh[2], (char*)As[1] + 2 * 8192 + dst16);
        load16_to_lds(qA_ + aTh[3], (char*)As[1] + 3 * 8192 + dst16);
        load16_to_lds(qB_ + bTh[0], (char*)Bs[1] + 0 * 8192 + dst16);
        load16_to_lds(qB_ + bTh[1], (char*)Bs[1] + 1 * 8192 + dst16);
    }
    asm volatile("s_waitcnt vmcnt(6)" ::: "memory");   // tile 0 resident
    __builtin_amdgcn_s_barrier();

    // main loop: 15 x 3 tiles (t=0..44), buffer indices compile-time
#pragma unroll 1
    for (int tt = 0; tt < 15; ++tt) {
        const int t = tt * 3;
        tile(IC<0>{}, IC<2>{}, t, true);
        asm volatile("s_waitcnt vmcnt(6)" ::: "memory");
        __builtin_amdgcn_s_barrier();
        tile(IC<1>{}, IC<0>{}, t + 1, true);
        asm volatile("s_waitcnt vmcnt(6)" ::: "memory");
        __builtin_amdgcn_s_barrier();
        tile(IC<2>{}, IC<1>{}, t + 2, true);
        asm volatile("s_waitcnt vmcnt(6)" ::: "memory");
        __builtin_amdgcn_s_barrier();
    }
    // t=45 (buf0): stages tile 47 -> buf2
    tile(IC<0>{}, IC<2>{}, 45, true);
    asm volatile("s_waitcnt vmcnt(6)" ::: "memory");   // tile 46 resident
    __builtin_amdgcn_s_barrier();
    // t=46 (buf1): no stage
    tile(IC<1>{}, IC<0>{}, 46, false);
    asm volatile("s_waitcnt vmcnt(0)" ::: "memory");   // tile 47 resident
    __builtin_amdgcn_s_barrier();
    // t=47 (buf2): no stage
    tile(IC<2>{}, IC<0>{}, 47, false);

    // epilogue: bias + relu + quantize (RNE matches jnp.round)
    const int colBase = n0 + wc * 64 + (lane & 15);
    const int rowBase = m0 + wr * 64 + ((lane >> 4) << 2);
#pragma unroll
    for (int i = 0; i < 4; ++i) {
#pragma unroll
        for (int j = 0; j < 4; ++j) {
            int col = colBase + j * 16;
            float bv = bias[col];
#pragma unroll
            for (int r = 0; r < 4; ++r) {
                int row = rowBase + i * 16 + r;
                float y = acc[i][j][r] + bv;
                y = fmaxf(y, 0.0f);
                y = rintf(y * 65536.0f) * (1.0f / 65536.0f);
                out[(size_t)row * 1024 + col] = y;
            }
        }
    }
}

// ---------------- fallback (ws too small): naive fp32 ----------------
__global__ __launch_bounds__(256) void naive_kernel(const float* __restrict__ x,
                                                    const float* __restrict__ w,
                                                    const float* __restrict__ bias,
                                                    float* __restrict__ out) {
    int idx = blockIdx.x * 256 + threadIdx.x;
    int row = idx >> 10, col = idx & 1023;
    float s = bias[col];
    for (int k = 0; k < 1024; ++k)
        s += x[(size_t)row * 1024 + k] * w[(size_t)k * 1024 + col];
    s = fmaxf(s, 0.0f);
    out[idx] = rintf(s * 65536.0f) * (1.0f / 65536.0f);
}

extern "C" void kernel_launch(void* const* d_in, const int* in_sizes, int n_in,
                              void* d_out, int out_size, void* d_ws, size_t ws_size,
                              hipStream_t stream) {
    const float* x = (const float*)d_in[0];
    const float* w = (const float*)d_in[1];
    const float* b = (const float*)d_in[2];
    float* out = (float*)d_out;

    const size_t needA = (size_t)8192 * 2048 * 2;   // 32 MB
    const size_t needB = (size_t)1024 * 2048 * 2;   //  4 MB
    if (ws_size < needA + needB) {
        naive_kernel<<<(8192 * 1024) / 256, 256, 0, stream>>>(x, w, b, out);
        return;
    }
    unsigned short* A2  = (unsigned short*)d_ws;
    unsigned short* Bt2 = (unsigned short*)((char*)d_ws + needA);

    split_x_kernel<<<(8192 * 1024 / 8) / 256, 256, 0, stream>>>(x, A2);
    split_w_kernel<<<dim3(32, 32), dim3(32, 32), 0, stream>>>(w, Bt2);
    gemm_kernel<<<256, 512, 0, stream>>>(A2, Bt2, b, out);
}